// Round 10
// baseline (8253.944 us; speedup 1.0000x reference)
//
#include <hip/hip_runtime.h>
#include <math.h>

#define B_ 4
#define L_ 2048
#define E_ 1024
#define H_ 16
#define D_ 64
#define FF_ 2816
#define M_ (B_*L_)     // 8192 rows
#define E4_ 4096
#define CH_ 64
#define NC_ (L_/CH_)   // 32 chunks

typedef unsigned short ushort_t;
typedef __attribute__((ext_vector_type(8))) short short8;
typedef __attribute__((ext_vector_type(4))) float f32x4;
typedef __attribute__((ext_vector_type(4))) unsigned short ushort4v;

__device__ inline ushort_t f2b(float x) {
  union { float f; unsigned u; } v; v.f = x;
  unsigned r = v.u + 0x7FFFu + ((v.u >> 16) & 1u);
  return (ushort_t)(r >> 16);
}
__device__ inline float b2f(ushort_t h) {
  union { unsigned u; float f; } v; v.u = ((unsigned)h) << 16; return v.f;
}

// ---------------------------------------------------------------------------
// reductions
// ---------------------------------------------------------------------------
__device__ inline float wave_sum(float a) {
#pragma unroll
  for (int off = 1; off < 64; off <<= 1) a += __shfl_xor(a, off);
  return a;
}
__device__ inline void wave_reduce2(float& a, float& b) {
#pragma unroll
  for (int off = 1; off < 64; off <<= 1) {
    a += __shfl_xor(a, off);
    b += __shfl_xor(b, off);
  }
}

// ---------------------------------------------------------------------------
// row LayerNorm over E_=1024 (two-pass variance), one block per row.
// ---------------------------------------------------------------------------
__global__ __launch_bounds__(256) void ln_rows(
    const float* __restrict__ in, const float* __restrict__ g,
    const float* __restrict__ bb, const float* __restrict__ res_after,
    float* __restrict__ outf, ushort_t* __restrict__ outb,
    ushort_t* __restrict__ outbl)
{
  int row = blockIdx.x;
  int t = threadIdx.x;
  float4 v = ((const float4*)(in + (size_t)row * E_))[t];
  float s = wave_sum(v.x + v.y + v.z + v.w);
  __shared__ float ra[4], rb[4];
  int w = t >> 6;
  if ((t & 63) == 0) ra[w] = s;
  __syncthreads();
  float mean = (ra[0] + ra[1] + ra[2] + ra[3]) * (1.f / E_);
  float dx = v.x - mean, dy = v.y - mean, dz = v.z - mean, dw = v.w - mean;
  float s2 = wave_sum(dx*dx + dy*dy + dz*dz + dw*dw);
  if ((t & 63) == 0) rb[w] = s2;
  __syncthreads();
  float var = (rb[0] + rb[1] + rb[2] + rb[3]) * (1.f / E_);
  float r = rsqrtf(var + 1e-5f);
  float4 gv = ((const float4*)g)[t];
  float4 bv = ((const float4*)bb)[t];
  float4 o;
  o.x = dx * r * gv.x + bv.x;
  o.y = dy * r * gv.y + bv.y;
  o.z = dz * r * gv.z + bv.z;
  o.w = dw * r * gv.w + bv.w;
  if (res_after) {
    float4 rv = ((const float4*)(res_after + (size_t)row * E_))[t];
    o.x += rv.x; o.y += rv.y; o.z += rv.z; o.w += rv.w;
  }
  if (outf) ((float4*)(outf + (size_t)row * E_))[t] = o;
  if (outb) {
    ushort4v hb; hb.x = f2b(o.x); hb.y = f2b(o.y); hb.z = f2b(o.z); hb.w = f2b(o.w);
    *(ushort4v*)(outb + (size_t)row * E_ + t * 4) = hb;
    if (outbl) {
      ushort4v lb;
      lb.x = f2b(o.x - b2f(hb.x)); lb.y = f2b(o.y - b2f(hb.y));
      lb.z = f2b(o.z - b2f(hb.z)); lb.w = f2b(o.w - b2f(hb.w));
      *(ushort4v*)(outbl + (size_t)row * E_ + t * 4) = lb;
    }
  }
}

// ---------------------------------------------------------------------------
// k <- k / max(||k||_2, 1e-5): f32 in, bf16 hi+lo out
// ---------------------------------------------------------------------------
__global__ __launch_bounds__(256) void knorm_rows(
    const float* __restrict__ kin, ushort_t* __restrict__ kh,
    ushort_t* __restrict__ kl)
{
  int row = blockIdx.x;
  int t = threadIdx.x;
  float4 v = ((const float4*)(kin + (size_t)row * E_))[t];
  float s2 = wave_sum(v.x*v.x + v.y*v.y + v.z*v.z + v.w*v.w);
  __shared__ float rb2[4];
  int w = t >> 6;
  if ((t & 63) == 0) rb2[w] = s2;
  __syncthreads();
  s2 = rb2[0] + rb2[1] + rb2[2] + rb2[3];
  float sc = 1.f / fmaxf(sqrtf(s2), 1e-5f);
  float f0 = v.x * sc, f1 = v.y * sc, f2 = v.z * sc, f3 = v.w * sc;
  ushort4v hb; hb.x = f2b(f0); hb.y = f2b(f1); hb.z = f2b(f2); hb.w = f2b(f3);
  ushort4v lb;
  lb.x = f2b(f0 - b2f(hb.x)); lb.y = f2b(f1 - b2f(hb.y));
  lb.z = f2b(f2 - b2f(hb.z)); lb.w = f2b(f3 - b2f(hb.w));
  *(ushort4v*)(kh + (size_t)row * E_ + t * 4) = hb;
  *(ushort4v*)(kl + (size_t)row * E_ + t * 4) = lb;
}

// ---------------------------------------------------------------------------
// cumsum helpers
// ---------------------------------------------------------------------------
__global__ __launch_bounds__(256) void chunk_partials(
    const float* __restrict__ x, float* __restrict__ S)
{
  int c = blockIdx.x, b = blockIdx.y, t = threadIdx.x;
  const float4* xp = (const float4*)(x + ((size_t)b * L_ + (size_t)c * CH_) * E_);
  float4 acc = make_float4(0.f, 0.f, 0.f, 0.f);
  for (int l = 0; l < CH_; ++l) {
    float4 v = xp[(size_t)l * (E_/4) + t];
    acc.x += v.x; acc.y += v.y; acc.z += v.z; acc.w += v.w;
  }
  ((float4*)(S + ((size_t)b * NC_ + c) * E_))[t] = acc;
}

__global__ __launch_bounds__(256) void scan_partials(float* __restrict__ S)
{
  int b = blockIdx.x, t = threadIdx.x;
  float4 run = make_float4(0.f, 0.f, 0.f, 0.f);
  for (int c = 0; c < NC_; ++c) {
    float4* p = (float4*)(S + ((size_t)b * NC_ + c) * E_);
    float4 v = p[t];
    p[t] = run;
    run.x += v.x; run.y += v.y; run.z += v.z; run.w += v.w;
  }
}

// ---------------------------------------------------------------------------
// align + gate (one wave per chunk,head,batch), two-pass LN
// ---------------------------------------------------------------------------
__global__ __launch_bounds__(64) void align_gate(
    const float* __restrict__ xmlp, const float* __restrict__ Sx,
    const float* __restrict__ gh, const float* __restrict__ bh,
    float* __restrict__ gated, float* __restrict__ G)
{
  int c = blockIdx.x, h = blockIdx.y, b = blockIdx.z;
  int d = threadIdx.x;
  int e = h * D_ + d;
  float xc = Sx[((size_t)b * NC_ + c) * E_ + e];
  float gsum = 0.f;
  float ghd = gh[d], bhd = bh[d];
  const float* xp = xmlp + ((size_t)b * L_ + (size_t)c * CH_) * E_ + e;
  float* gp = gated + ((size_t)b * L_ + (size_t)c * CH_) * E_ + e;
  for (int l = 0; l < CH_; ++l) {
    float xv = xp[(size_t)l * E_];
    xc += xv;
    float sx = xv, sc = xc;
    wave_reduce2(sx, sc);
    float mx = sx * (1.f/64.f), mc = sc * (1.f/64.f);
    float dx = xv - mx, dc = xc - mc;
    float vx = dx * dx, vc = dc * dc;
    wave_reduce2(vx, vc);
    vx *= (1.f/64.f); vc *= (1.f/64.f);
    float nx  = dx * rsqrtf(vx + 1e-5f) * ghd + bhd;
    float ncv = dc * rsqrtf(vc + 1e-5f) * ghd + bhd;
    float dotv = wave_sum(nx * ncv);
    float align = dotv * 0.125f;
    float sig = 1.f / (1.f + expf(-align));
    float gv = xv * sig;
    gp[(size_t)l * E_] = gv;
    gsum += gv;
  }
  G[((size_t)b * NC_ + c) * E_ + e] = gsum;
}

// ---------------------------------------------------------------------------
// t = x_mlp + cumsum(gated)
// ---------------------------------------------------------------------------
__global__ __launch_bounds__(256) void context_add(
    const float* __restrict__ gated, const float* __restrict__ Gx,
    const float* __restrict__ xmlp, float* __restrict__ t_out)
{
  int c = blockIdx.x, b = blockIdx.y, t = threadIdx.x;
  float4 run = ((const float4*)(Gx + ((size_t)b * NC_ + c) * E_))[t];
  size_t base = ((size_t)b * L_ + (size_t)c * CH_) * (E_/4);
  const float4* gp = (const float4*)gated;
  const float4* xp = (const float4*)xmlp;
  float4* op = (float4*)t_out;
  for (int l = 0; l < CH_; ++l) {
    size_t idx = base + (size_t)l * (E_/4) + t;
    float4 g = gp[idx];
    run.x += g.x; run.y += g.y; run.z += g.z; run.w += g.w;
    float4 x = xp[idx];
    float4 o;
    o.x = x.x + run.x; o.y = x.y + run.y; o.z = x.z + run.z; o.w = x.w + run.w;
    op[idx] = o;
  }
}

// ---------------------------------------------------------------------------
// transpose + convert: f32 (R x C) -> bf16 (C x R), hi + optional lo plane
// ---------------------------------------------------------------------------
__global__ __launch_bounds__(256) void wcvt_t(
    const float* __restrict__ in, ushort_t* __restrict__ outh,
    ushort_t* __restrict__ outl, int R, int C)
{
  __shared__ float t[32][33];
  int c0 = blockIdx.x * 32, r0 = blockIdx.y * 32;
  int tid = threadIdx.x;
  int r = tid >> 3, c4 = (tid & 7) * 4;
  float4 v = *(const float4*)(in + (size_t)(r0 + r) * C + c0 + c4);
  t[r][c4] = v.x; t[r][c4+1] = v.y; t[r][c4+2] = v.z; t[r][c4+3] = v.w;
  __syncthreads();
  int c = tid >> 3, r4 = (tid & 7) * 4;
  float f0 = t[r4][c], f1 = t[r4+1][c], f2 = t[r4+2][c], f3 = t[r4+3][c];
  ushort4v hb; hb.x = f2b(f0); hb.y = f2b(f1); hb.z = f2b(f2); hb.w = f2b(f3);
  *(ushort4v*)(outh + (size_t)(c0 + c) * R + r0 + r4) = hb;
  if (outl) {
    ushort4v lb;
    lb.x = f2b(f0 - b2f(hb.x)); lb.y = f2b(f1 - b2f(hb.y));
    lb.z = f2b(f2 - b2f(hb.z)); lb.w = f2b(f3 - b2f(hb.w));
    *(ushort4v*)(outl + (size_t)(c0 + c) * R + r0 + r4) = lb;
  }
}

// f32 [B][L][E] ->(scale 1/32)-> 2-plane bf16 [B][E][L]
__global__ __launch_bounds__(256) void tpose_f2p(
    const float* __restrict__ in, ushort_t* __restrict__ outh,
    ushort_t* __restrict__ outl)
{
  __shared__ float t[32][33];
  int b = blockIdx.z;
  const float* ib = in + (size_t)b * L_ * E_;
  size_t ob = (size_t)b * E_ * L_;
  int c0 = blockIdx.x * 32, r0 = blockIdx.y * 32;   // c over E, r over L
  int tid = threadIdx.x;
  int r = tid >> 3, c4 = (tid & 7) * 4;
  float4 v = *(const float4*)(ib + (size_t)(r0 + r) * E_ + c0 + c4);
  t[r][c4] = v.x; t[r][c4+1] = v.y; t[r][c4+2] = v.z; t[r][c4+3] = v.w;
  __syncthreads();
  int c = tid >> 3, r4 = (tid & 7) * 4;
  const float S = 0.03125f;   // fold /32 into v_dynT (exact: pow2 scale)
  float f0 = t[r4][c]*S, f1 = t[r4+1][c]*S, f2 = t[r4+2][c]*S, f3 = t[r4+3][c]*S;
  ushort4v hb; hb.x = f2b(f0); hb.y = f2b(f1); hb.z = f2b(f2); hb.w = f2b(f3);
  ushort4v lb;
  lb.x = f2b(f0 - b2f(hb.x)); lb.y = f2b(f1 - b2f(hb.y));
  lb.z = f2b(f2 - b2f(hb.z)); lb.w = f2b(f3 - b2f(hb.w));
  size_t oidx = ob + (size_t)(c0 + c) * L_ + r0 + r4;
  *(ushort4v*)(outh + oidx) = hb;
  *(ushort4v*)(outl + oidx) = lb;
}

// zero the strictly-above-diagonal 128x128 tiles of scores f32 output
__global__ __launch_bounds__(256) void zero_upper(float* __restrict__ sc)
{
  int bx = blockIdx.x, by = blockIdx.y, z = blockIdx.z;
  if (bx <= by) return;
  float* base = sc + (size_t)z * L_ * L_;
  int t = threadIdx.x;
  float4 zf = make_float4(0.f, 0.f, 0.f, 0.f);
#pragma unroll
  for (int i = 0; i < 16; ++i) {
    int e = t + 256 * i;
    int r = e >> 5, c4 = (e & 31) * 4;
    *(float4*)(base + (size_t)(by * 128 + r) * L_ + bx * 128 + c4) = zf;
  }
}

// ---------------------------------------------------------------------------
// GEMM parameter block (shared by both kernels)
// ---------------------------------------------------------------------------
enum { EPI_PLAIN = 0, EPI_BIAS = 1, EPI_SILU = 2, EPI_SIG = 3,
       EPI_BIAS_RES = 4, EPI_VDYN = 5, EPI_SCL32 = 6, EPI_TRIL = 7,
       EPI_QKVG = 9 };

struct GemmP {
  const ushort_t *A, *Al, *Bt, *Btl;
  const ushort_t *A2, *A2l, *Bt2, *Bt2l;
  float *Cf, *Cf2, *Cf3;
  ushort_t *Cb, *Cbl;
  int N, K, ldA, ldB, K2, ldA2, ldB2;
  long long sA, sB, sA2, sB2, sCf, sCb, sRes;
  const float *bias, *bias1, *bias2, *bias3, *res, *aux;
  int epi, causal;
};

// ---------------------------------------------------------------------------
// gemm_k: 128x128 tile, 4 waves 64x64 (proven causal/batched core).
// MODE 0: plain bf16.  MODE 1: split 2-plane (3-pass).
// LDS [kw][plane][slot][8], slot = m^(kw<<1) (measured: 0 bank conflicts).
// Optional second K-segment accumulated into same acc.
// causal: 0 none, 2 kend=row0+128, 3 triangular-packed grid decode.
// ---------------------------------------------------------------------------
template <int MODE>
__global__ __launch_bounds__(256) void gemm_k(GemmP p)
{
  constexpr int NP = (MODE == 1) ? 2 : 1;
  __shared__ __align__(16) short As[4][NP][128][8];
  __shared__ __align__(16) short Bs[4][NP][128][8];

  int z = blockIdx.z;
  int bx = blockIdx.x, by = blockIdx.y;
  if (p.causal == 3) {            // triangular-packed: bx in [0, T(nry))
    int ti = bx;
    int ry = (int)((sqrtf(8.f * ti + 1.f) - 1.f) * 0.5f);
    while ((ry + 1) * (ry + 2) / 2 <= ti) ++ry;
    while (ry * (ry + 1) / 2 > ti) --ry;
    by = ry; bx = ti - ry * (ry + 1) / 2;
  }
  int row0 = by * 128, col0 = bx * 128;
  int tid = threadIdx.x;
  int lane = tid & 63, wv = tid >> 6;
  int wm = wv >> 1, wn = wv & 1;
  int lr = lane & 15, kq = lane >> 4;
  int lrx = lr ^ (kq << 1);
  int kw = tid & 3, m0 = tid >> 2, m1 = m0 + 64;
  int sl0 = m0 ^ (kw << 1), sl1 = m1 ^ (kw << 1);

  f32x4 acc[4][4] = {};

  auto kloop = [&](const ushort_t* AH, const ushort_t* ALo,
                   const ushort_t* BH, const ushort_t* BLo,
                   int ldA, int ldB, int kend) {
    size_t aoff0 = (size_t)(row0 + m0) * ldA + kw * 8;
    size_t aoff1 = (size_t)(row0 + m1) * ldA + kw * 8;
    size_t boff0 = (size_t)(col0 + m0) * ldB + kw * 8;
    size_t boff1 = (size_t)(col0 + m1) * ldB + kw * 8;
    short8 a0h, a1h, b0h, b1h, a0l, a1l, b0l, b1l;
    a0h = *(const short8*)(AH + aoff0);
    a1h = *(const short8*)(AH + aoff1);
    b0h = *(const short8*)(BH + boff0);
    b1h = *(const short8*)(BH + boff1);
    if constexpr (MODE == 1) {
      a0l = *(const short8*)(ALo + aoff0);
      a1l = *(const short8*)(ALo + aoff1);
      b0l = *(const short8*)(BLo + boff0);
      b1l = *(const short8*)(BLo + boff1);
    }
    for (int k0 = 0; k0 < kend; k0 += 32) {
      __syncthreads();                  // previous tile's reads complete
      *(short8*)&As[kw][0][sl0][0] = a0h;
      *(short8*)&As[kw][0][sl1][0] = a1h;
      *(short8*)&Bs[kw][0][sl0][0] = b0h;
      *(short8*)&Bs[kw][0][sl1][0] = b1h;
      if constexpr (MODE == 1) {
        *(short8*)&As[kw][NP-1][sl0][0] = a0l;
        *(short8*)&As[kw][NP-1][sl1][0] = a1l;
        *(short8*)&Bs[kw][NP-1][sl0][0] = b0l;
        *(short8*)&Bs[kw][NP-1][sl1][0] = b1l;
      }
      __syncthreads();
      if (k0 + 32 < kend) {             // prefetch next tile (overlaps MFMA)
        size_t kk = (size_t)k0 + 32;
        a0h = *(const short8*)(AH + aoff0 + kk);
        a1h = *(const short8*)(AH + aoff1 + kk);
        b0h = *(const short8*)(BH + boff0 + kk);
        b1h = *(const short8*)(BH + boff1 + kk);
        if constexpr (MODE == 1) {
          a0l = *(const short8*)(ALo + aoff0 + kk);
          a1l = *(const short8*)(ALo + aoff1 + kk);
          b0l = *(const short8*)(BLo + boff0 + kk);
          b1l = *(const short8*)(BLo + boff1 + kk);
        }
      }
      short8 bh[4], bl[4];
#pragma unroll
      for (int ni = 0; ni < 4; ++ni) {
        bh[ni] = *(const short8*)&Bs[kq][0][wn * 64 + ni * 16 + lrx][0];
        if constexpr (MODE == 1)
          bl[ni] = *(const short8*)&Bs[kq][NP-1][wn * 64 + ni * 16 + lrx][0];
      }
#pragma unroll
      for (int mi = 0; mi < 4; ++mi) {
        short8 ah = *(const short8*)&As[kq][0][wm * 64 + mi * 16 + lrx][0];
        short8 al;
        if constexpr (MODE == 1)
          al = *(const short8*)&As[kq][NP-1][wm * 64 + mi * 16 + lrx][0];
#pragma unroll
        for (int ni = 0; ni < 4; ++ni) {
          acc[mi][ni] = __builtin_amdgcn_mfma_f32_16x16x32_bf16(
              ah, bh[ni], acc[mi][ni], 0, 0, 0);
          if constexpr (MODE == 1) {
            acc[mi][ni] = __builtin_amdgcn_mfma_f32_16x16x32_bf16(
                al, bh[ni], acc[mi][ni], 0, 0, 0);
            acc[mi][ni] = __builtin_amdgcn_mfma_f32_16x16x32_bf16(
                ah, bl[ni], acc[mi][ni], 0, 0, 0);
          }
        }
      }
    }
  };

  int kend = p.K;
  if (p.causal == 2) { int ke = row0 + 128; kend = ke < p.K ? ke : p.K; }
  {
    const ushort_t* Ah = p.A  + (size_t)z * p.sA;
    const ushort_t* Bh = p.Bt + (size_t)z * p.sB;
    const ushort_t* Alo = (MODE == 1) ? p.Al  + (size_t)z * p.sA : nullptr;
    const ushort_t* Blo = (MODE == 1) ? p.Btl + (size_t)z * p.sB : nullptr;
    kloop(Ah, Alo, Bh, Blo, p.ldA, p.ldB, kend);
  }
  if (p.K2 > 0) {
    const ushort_t* Ah = p.A2  + (size_t)z * p.sA2;
    const ushort_t* Bh = p.Bt2 + (size_t)z * p.sB2;
    const ushort_t* Alo = (MODE == 1) ? p.A2l  + (size_t)z * p.sA2 : nullptr;
    const ushort_t* Blo = (MODE == 1) ? p.Bt2l + (size_t)z * p.sB2 : nullptr;
    kloop(Ah, Alo, Bh, Blo, p.ldA2, p.ldB2, p.K2);
  }

  int rbase = kq * 4;   // D row = (lane>>4)*4 + reg
  const float INV32 = 0.03125f;

  float* Cf = p.Cf ? p.Cf + (size_t)z * p.sCf : nullptr;
  ushort_t* Cb  = p.Cb  ? p.Cb  + (size_t)z * p.sCb : nullptr;
  ushort_t* Cbl = p.Cbl ? p.Cbl + (size_t)z * p.sCb : nullptr;
  const float* res = p.res ? p.res + (size_t)z * p.sRes : nullptr;

#pragma unroll
  for (int mi = 0; mi < 4; ++mi) {
#pragma unroll
    for (int r = 0; r < 4; ++r) {
      int grow = row0 + wm * 64 + mi * 16 + rbase + r;
      size_t rowoff = (size_t)grow * p.N;
#pragma unroll
      for (int ni = 0; ni < 4; ++ni) {
        int gcol = col0 + wn * 64 + ni * 16 + lr;
        size_t idx = rowoff + gcol;
        float v = acc[mi][ni][r];
        switch (p.epi) {
          case EPI_PLAIN: break;
          case EPI_BIAS: v += p.bias[gcol]; break;
          case EPI_SILU: v += p.bias[gcol]; v = v / (1.f + expf(-v)); break;
          case EPI_SIG:  v = 1.f / (1.f + expf(-(v + p.bias[gcol]))); break;
          case EPI_BIAS_RES: v += p.bias[gcol] + res[idx]; break;
          case EPI_VDYN: v = p.aux[idx] * (res[idx] - v * INV32); break;
          case EPI_SCL32: v *= INV32; break;
          case EPI_TRIL: v = (gcol <= grow) ? v : 0.f; break;
        }
        if (Cf) Cf[idx] = v;
        if (Cb) {
          ushort_t hi = f2b(v);
          Cb[idx] = hi;
          if (Cbl) Cbl[idx] = f2b(v - b2f(hi));
        }
      }
    }
  }
}

// ---------------------------------------------------------------------------
// gemm_big: 256x128 tile, 4 waves 128x64 — higher FLOP/LDS-byte for the
// LDS-BW-bound uniform GEMMs.  Explicit scalar staging regs (no arrays, no
// lambda — round-8 spill post-mortem).  nb==1, no causal, no K2.
// ---------------------------------------------------------------------------
template <int MODE>
__global__ __launch_bounds__(256) void gemm_big(GemmP p)
{
  constexpr int NP = (MODE == 1) ? 2 : 1;
  __shared__ __align__(16) short As[4][NP][256][8];
  __shared__ __align__(16) short Bs[4][NP][128][8];

  int row0 = blockIdx.y * 256, col0 = blockIdx.x * 128;
  int tid = threadIdx.x;
  int lane = tid & 63, wv = tid >> 6;
  int wm = wv >> 1, wn = wv & 1;          // wave tile 128x64
  int lr = lane & 15, kq = lane >> 4;
  int lrx = lr ^ (kq << 1);
  int kw = tid & 3, mb = tid >> 2;        // mb in [0,64)
  int sl = mb ^ (kw << 1);

  const ushort_t* Ah = p.A;
  const ushort_t* Bh = p.Bt;
  const ushort_t* Alo = p.Al;
  const ushort_t* Blo = p.Btl;

  size_t a0 = (size_t)(row0 + mb) * p.ldA + kw * 8;
  size_t b0 = (size_t)(col0 + mb) * p.ldB + kw * 8;
  size_t dA = (size_t)64 * p.ldA;
  size_t dB = (size_t)64 * p.ldB;

  f32x4 acc[8][4] = {};

  short8 a0h, a1h, a2h, a3h, b0h, b1h;
  short8 a0l, a1l, a2l, a3l, b0l, b1l;
  a0h = *(const short8*)(Ah + a0);
  a1h = *(const short8*)(Ah + a0 + dA);
  a2h = *(const short8*)(Ah + a0 + 2*dA);
  a3h = *(const short8*)(Ah + a0 + 3*dA);
  b0h = *(const short8*)(Bh + b0);
  b1h = *(const short8*)(Bh + b0 + dB);
  if constexpr (MODE == 1) {
    a0l = *(const short8*)(Alo + a0);
    a1l = *(const short8*)(Alo + a0 + dA);
    a2l = *(const short8*)(Alo + a0 + 2*dA);
    a3l = *(const short8*)(Alo + a0 + 3*dA);
    b0l = *(const short8*)(Blo + b0);
    b1l = *(const short8*)(Blo + b0 + dB);
  }

  for (int k0 = 0; k0 < p.K; k0 += 32) {
    __syncthreads();
    *(short8*)&As[kw][0][sl      ][0] = a0h;
    *(short8*)&As[kw][0][sl +  64][0] = a1h;
    *(short8*)&As[kw][0][sl + 128][0] = a2h;
    *(short8*)&As[kw][0][sl + 192][0] = a3h;
    *(short8*)&Bs[kw][0][sl      ][0] = b0h;
    *(short8*)&Bs[kw][0][sl +  64][0] = b1h;
    if constexpr (MODE == 1) {
      *(short8*)&As[kw][NP-1][sl      ][0] = a0l;
      *(short8*)&As[kw][NP-1][sl +  64][0] = a1l;
      *(short8*)&As[kw][NP-1][sl + 128][0] = a2l;
      *(short8*)&As[kw][NP-1][sl + 192][0] = a3l;
      *(short8*)&Bs[kw][NP-1][sl      ][0] = b0l;
      *(short8*)&Bs[kw][NP-1][sl +  64][0] = b1l;
    }
    __syncthreads();
    if (k0 + 32 < p.K) {
      size_t kk = (size_t)k0 + 32;
      a0h = *(const short8*)(Ah + a0 + kk);
      a1h = *(const short8*)(Ah + a0 + dA + kk);
      a2h = *(const short8*)(Ah + a0 + 2*dA + kk);
      a3h = *(const short8*)(Ah + a0 + 3*dA + kk);
      b0h = *(const short8*)(Bh + b0 + kk);
      b1h = *(const short8*)(Bh + b0 + dB + kk);
      if constexpr (MODE == 1) {
        a0l = *(const short8*)(Alo + a0 + kk);
        a1l = *(const short8*)(Alo + a0 + dA + kk);
        a2l = *(const short8*)(Alo + a0 + 2*dA + kk);
        a3l = *(const short8*)(Alo + a0 + 3*dA + kk);
        b0l = *(const short8*)(Blo + b0 + kk);
        b1l = *(const short8*)(Blo + b0 + dB + kk);
      }
    }
    short8 bh[4], bl[4];
#pragma unroll
    for (int ni = 0; ni < 4; ++ni) {
      bh[ni] = *(const short8*)&Bs[kq][0][wn * 64 + ni * 16 + lrx][0];
      if constexpr (MODE == 1)
        bl[ni] = *(const short8*)&Bs[kq][NP-1][wn * 64 + ni * 16 + lrx][0];
    }
#pragma unroll
    for (int mi = 0; mi < 8; ++mi) {
      short8 ah = *(const short8*)&As[kq][0][wm * 128 + mi * 16 + lrx][0];
      short8 al;
      if constexpr (MODE == 1)
        al = *(const short8*)&As[kq][NP-1][wm * 128 + mi * 16 + lrx][0];
#pragma unroll
      for (int ni = 0; ni < 4; ++ni) {
        acc[mi][ni] = __builtin_amdgcn_mfma_f32_16x16x32_bf16(
            ah, bh[ni], acc[mi][ni], 0, 0, 0);
        if constexpr (MODE == 1) {
          acc[mi][ni] = __builtin_amdgcn_mfma_f32_16x16x32_bf16(
              al, bh[ni], acc[mi][ni], 0, 0, 0);
          acc[mi][ni] = __builtin_amdgcn_mfma_f32_16x16x32_bf16(
              ah, bl[ni], acc[mi][ni], 0, 0, 0);
        }
      }
    }
  }

  int rbase = kq * 4;
  const float INV32 = 0.03125f;

  if (p.epi == EPI_QKVG) {              // fused q|k|v|gate, group per block
    int gi = col0 >> 10;
    int cb0 = col0 & 1023;
    const float* gb = gi == 0 ? p.bias : gi == 1 ? p.bias1
                    : gi == 2 ? p.bias2 : p.bias3;
#pragma unroll
    for (int mi = 0; mi < 8; ++mi) {
#pragma unroll
      for (int r = 0; r < 4; ++r) {
        int grow = row0 + wm * 128 + mi * 16 + rbase + r;
        size_t rowoff = (size_t)grow * 1024;
#pragma unroll
        for (int ni = 0; ni < 4; ++ni) {
          int gc = cb0 + wn * 64 + ni * 16 + lr;
          size_t idx = rowoff + gc;
          float v = acc[mi][ni][r] + gb[gc];
          if (gi == 0) {
            ushort_t hi = f2b(v);
            p.Cb[idx] = hi;
            p.Cbl[idx] = f2b(v - b2f(hi));
          } else if (gi == 1) p.Cf[idx] = v;
          else if (gi == 2) p.Cf2[idx] = v;
          else p.Cf3[idx] = 1.f / (1.f + expf(-v));
        }
      }
    }
    return;
  }

#pragma unroll
  for (int mi = 0; mi < 8; ++mi) {
#pragma unroll
    for (int r = 0; r < 4; ++r) {
      int grow = row0 + wm * 128 + mi * 16 + rbase + r;
      size_t rowoff = (size_t)grow * p.N;
#pragma unroll
      for (int ni = 0; ni < 4; ++ni) {
        int gcol = col0 + wn * 64 + ni * 16 + lr;
        size_t idx = rowoff + gcol;
        float v = acc[mi][ni][r];
        switch (p.epi) {
          case EPI_PLAIN: break;
          case EPI_BIAS: v += p.bias[gcol]; break;
          case EPI_SILU: v += p.bias[gcol]; v = v / (1.f + expf(-v)); break;
          case EPI_SIG:  v = 1.f / (1.f + expf(-(v + p.bias[gcol]))); break;
          case EPI_BIAS_RES: v += p.bias[gcol] + p.res[idx]; break;
          case EPI_VDYN: v = p.aux[idx] * (p.res[idx] - v * INV32); break;
          case EPI_SCL32: v *= INV32; break;
        }
        if (p.Cf) p.Cf[idx] = v;
        if (p.Cb) {
          ushort_t hi = f2b(v);
          p.Cb[idx] = hi;
          if (p.Cbl) p.Cbl[idx] = f2b(v - b2f(hi));
        }
      }
    }
  }
}

// ---------------------------------------------------------------------------
// host orchestration
// ---------------------------------------------------------------------------
static void run_gemm(const GemmP& p, int M, int nb, int mode, hipStream_t s)
{
  dim3 grid(p.N / 128, M / 128, nb), blk(256);
  if (mode == 0) gemm_k<0><<<grid, blk, 0, s>>>(p);
  else           gemm_k<1><<<grid, blk, 0, s>>>(p);
}

static void run_big(const GemmP& p, int M, int mode, hipStream_t s)
{
  dim3 grid(p.N / 128, M / 256, 1), blk(256);
  if (mode == 0) gemm_big<0><<<grid, blk, 0, s>>>(p);
  else           gemm_big<1><<<grid, blk, 0, s>>>(p);
}

extern "C" void kernel_launch(void* const* d_in, const int* in_sizes, int n_in,
                              void* d_out, int out_size, void* d_ws, size_t ws_size,
                              hipStream_t stream)
{
  const float* x      = (const float*)d_in[0];
  const float* g_norm = (const float*)d_in[1];
  const float* b_norm = (const float*)d_in[2];
  const float* W1     = (const float*)d_in[3];
  const float* b1     = (const float*)d_in[4];
  const float* W2     = (const float*)d_in[5];
  const float* b2     = (const float*)d_in[6];
  const float* g_head = (const float*)d_in[7];
  const float* b_head = (const float*)d_in[8];
  const float* memW   = (const float*)d_in[9];
  const float* g_mem  = (const float*)d_in[10];
  const float* b_mem  = (const float*)d_in[11];
  const float* W_q    = (const float*)d_in[12];
  const float* b_q    = (const float*)d_in[13];
  const float* W_k    = (const float*)d_in[14];
  const float* b_k    = (const float*)d_in[15];
  const float* W_v    = (const float*)d_in[16];
  const float* b_v    = (const float*)d_in[17];
  const float* W_g    = (const float*)d_in[18];
  const float* b_g    = (const float*)d_in[19];
  const float* W_o    = (const float*)d_in[22];
  const float* b_o    = (const float*)d_in[23];
  const float* W_op   = (const float*)d_in[24];
  const float* b_op   = (const float*)d_in[25];
  const float* g_ctx  = (const float*)d_in[26];
  const float* b_ctx  = (const float*)d_in[27];

  float* out = (float*)d_out;
  char* w = (char*)d_ws;
  auto alloc = [&](size_t bytes) { char* p = w; w += (bytes + 255) & ~(size_t)255; return p; };

  const size_t ME  = (size_t)M_ * E_;
  const size_t EE  = (size_t)E_ * E_;
  const size_t E4E = (size_t)E_ * E4_;
  const size_t BLL = (size_t)B_ * L_ * L_;

  ushort_t* W1t  = (ushort_t*)alloc((size_t)FF_ * E_ * 2);
  ushort_t* W2t  = (ushort_t*)alloc((size_t)E_ * FF_ * 2);
  ushort_t* W4   = (ushort_t*)alloc(8 * EE * 2);          // q|k|v|g hi then lo
  ushort_t* memT = (ushort_t*)alloc(2 * EE * 2);
  ushort_t* Wot  = (ushort_t*)alloc(2 * E4E * 2);
  ushort_t* Wopt = (ushort_t*)alloc(2 * E4E * 2);
  float* P0 = (float*)alloc(ME * 4);   // xmlp (live to end)
  float* P1 = (float*)alloc(ME * 4);   // gated->kraw->vdyn->out
  float* P2 = (float*)alloc(ME * 4);   // t->v->vdynT2p->outacc
  ushort_t* Q1 = (ushort_t*)alloc(2 * ME * 2);  // xnormH/ctx2p -> memout2p
  ushort_t* Q2 = (ushort_t*)alloc(2 * ME * 2);  // q2p
  ushort_t* Q3 = (ushort_t*)alloc(2 * ME * 2);  // k2p
  ushort_t* SH = (ushort_t*)alloc(2 * BLL * 2); // h1 | gateF | scores2p | outh2p
  float* Sb = (float*)alloc((size_t)B_ * NC_ * E_ * 4);
  float* Gb = (float*)alloc((size_t)B_ * NC_ * E_ * 4);
  if ((size_t)(w - (char*)d_ws) > ws_size) return;

  float* y_out  = out;
  float* sc_out = out + ME;
  ushort_t* P2u = (ushort_t*)P2;
  float* gateF  = (float*)SH;

  // weight conversion + transpose (f32 RxC -> bf16 CxR planes)
  wcvt_t<<<dim3(FF_/32, E_/32),  256, 0, stream>>>(W1,   W1t,  nullptr,        E_,  FF_);
  wcvt_t<<<dim3(E_/32,  FF_/32), 256, 0, stream>>>(W2,   W2t,  nullptr,        FF_, E_);
  wcvt_t<<<dim3(E_/32,  E_/32),  256, 0, stream>>>(W_q,  W4,        W4 + 4*EE, E_, E_);
  wcvt_t<<<dim3(E_/32,  E_/32),  256, 0, stream>>>(W_k,  W4 + EE,   W4 + 5*EE, E_, E_);
  wcvt_t<<<dim3(E_/32,  E_/32),  256, 0, stream>>>(W_v,  W4 + 2*EE, W4 + 6*EE, E_, E_);
  wcvt_t<<<dim3(E_/32,  E_/32),  256, 0, stream>>>(W_g,  W4 + 3*EE, W4 + 7*EE, E_, E_);
  wcvt_t<<<dim3(E_/32,  E_/32),  256, 0, stream>>>(memW, memT, memT + EE,      E_,  E_);
  wcvt_t<<<dim3(E4_/32, E_/32),  256, 0, stream>>>(W_o,  Wot,  Wot + E4E,      E_,  E4_);
  wcvt_t<<<dim3(E_/32,  E4_/32), 256, 0, stream>>>(W_op, Wopt, Wopt + E4E,     E4_, E_);

  GemmP p{};

  // 1. x_norm = LN(x) -> bf16 hi (Q1)
  ln_rows<<<M_, 256, 0, stream>>>(x, g_norm, b_norm, nullptr, nullptr, Q1, nullptr);
  // 2. h1 = silu(x_norm @ W1 + b1) -> SH plain bf16   [BIG MODE0]
  p = GemmP{}; p.A = Q1; p.Bt = W1t; p.Cb = SH;
  p.N = FF_; p.K = E_; p.ldA = E_; p.ldB = E_;
  p.bias = b1; p.epi = EPI_SILU;
  run_big(p, M_, 0, stream);
  // 3. x_mlp = x + h1 @ W2 + b2 -> P0   [BIG MODE0]
  p = GemmP{}; p.A = SH; p.Bt = W2t; p.Cf = P0;
  p.N = E_; p.K = FF_; p.ldA = FF_; p.ldB = FF_;
  p.bias = b2; p.res = x; p.epi = EPI_BIAS_RES;
  run_big(p, M_, 0, stream);
  // 4-8. cumsum gating chain
  chunk_partials<<<dim3(NC_, B_), 256, 0, stream>>>(P0, Sb);
  scan_partials<<<B_, 256, 0, stream>>>(Sb);
  align_gate<<<dim3(NC_, H_, B_), 64, 0, stream>>>(P0, Sb, g_head, b_head, P1, Gb);
  scan_partials<<<B_, 256, 0, stream>>>(Gb);
  context_add<<<dim3(NC_, B_), 256, 0, stream>>>(P1, Gb, P0, P2);
  // 9. ctx = LN(t) -> Q1 2p
  ln_rows<<<M_, 256, 0, stream>>>(P2, g_mem, b_mem, nullptr, nullptr, Q1, Q1 + ME);
  // 10. fused QKVG (N=4096): q->Q2 2p, kraw->P1, v->P2, gate->gateF   [BIG]
  p = GemmP{}; p.A = Q1; p.Al = Q1 + ME; p.Bt = W4; p.Btl = W4 + 4*EE;
  p.N = E4_; p.K = E_; p.ldA = E_; p.ldB = E_;
  p.Cb = Q2; p.Cbl = Q2 + ME; p.Cf = P1; p.Cf2 = P2; p.Cf3 = gateF;
  p.bias = b_q; p.bias1 = b_k; p.bias2 = b_v; p.bias3 = b_g;
  p.epi = EPI_QKVG;
  run_big(p, M_, 1, stream);
  // 11. knorm: P1(kraw) -> Q3 2p
  knorm_rows<<<M_, 256, 0, stream>>>(P1, Q3, Q3 + ME);
  // 12. v_dyn = gate * (v - (k @ mem)/32) -> P1 f32   [BIG]
  p = GemmP{}; p.A = Q3; p.Al = Q3 + ME; p.Bt = memT; p.Btl = memT + EE;
  p.N = E_; p.K = E_; p.ldA = E_; p.ldB = E_;
  p.Cf = P1; p.res = P2; p.aux = gateF; p.epi = EPI_VDYN;
  run_big(p, M_, 1, stream);
  // 13. vdynT/32 2p [B][E][L] -> P2u planes
  tpose_f2p<<<dim3(E_/32, L_/32, B_), 256, 0, stream>>>(P1, P2u, P2u + ME);
  // 14a. zero upper triangle of f32 scores output
  zero_upper<<<dim3(16, 16, B_), 256, 0, stream>>>(sc_out);
  // 14b. scores = tril(q @ k^T) -> f32 d_out + 2p SH  [triangular grid]
  p = GemmP{}; p.A = Q2; p.Al = Q2 + ME; p.Bt = Q3; p.Btl = Q3 + ME;
  p.N = L_; p.K = E_; p.ldA = E_; p.ldB = E_;
  p.sA = (long long)L_ * E_; p.sB = (long long)L_ * E_;
  p.Cf = sc_out; p.sCf = (long long)L_ * L_;
  p.Cb = SH; p.Cbl = SH + BLL; p.sCb = (long long)L_ * L_;
  p.epi = EPI_TRIL; p.causal = 3;
  gemm_k<1><<<dim3(136, 1, B_), 256, 0, stream>>>(p);
  // 15. mem_out = (q@mem + scores@(v_dyn/32))/32 -> Q1 2p  [fused 2-segment]
  p = GemmP{}; p.A = SH; p.Al = SH + BLL; p.Bt = P2u; p.Btl = P2u + ME;
  p.N = E_; p.K = L_; p.ldA = L_; p.ldB = L_;
  p.sA = (long long)L_ * L_; p.sB = (long long)E_ * L_;
  p.A2 = Q2; p.A2l = Q2 + ME; p.Bt2 = memT; p.Bt2l = memT + EE;
  p.K2 = E_; p.ldA2 = E_; p.ldB2 = E_;
  p.sA2 = (long long)L_ * E_; p.sB2 = 0;
  p.Cb = Q1; p.Cbl = Q1 + ME; p.sCb = (long long)L_ * E_;
  p.epi = EPI_SCL32; p.causal = 2;
  run_gemm(p, L_, B_, 1, stream);
  // 16-17. output MLP, E4 chunked by 2048   [BIG]
  const size_t SHLO = (size_t)M_ * 2048;
  for (int c = 0; c < 2; ++c) {
    p = GemmP{}; p.A = Q1; p.Al = Q1 + ME;
    p.Bt = Wot + (size_t)c * 2048 * E_; p.Btl = Wot + E4E + (size_t)c * 2048 * E_;
    p.N = 2048; p.K = E_; p.ldA = E_; p.ldB = E_;
    p.Cb = SH; p.Cbl = SH + SHLO;
    p.bias = b_o + c * 2048; p.epi = EPI_SILU;
    run_big(p, M_, 1, stream);
    p = GemmP{}; p.A = SH; p.Al = SH + SHLO;
    p.Bt = Wopt + (size_t)c * 2048; p.Btl = Wopt + E4E + (size_t)c * 2048;
    p.N = E_; p.K = 2048; p.ldA = 2048; p.ldB = E4_;
    if (c == 0) { p.Cf = P2; p.epi = EPI_PLAIN; }
    else { p.Cf = P1; p.res = P2; p.bias = b_op; p.epi = EPI_BIAS_RES; }
    run_big(p, M_, 1, stream);
  }
  // 18. y = x_mlp + LN(out)
  ln_rows<<<M_, 256, 0, stream>>>(P1, g_ctx, b_ctx, P0, y_out, nullptr, nullptr);
}

// Round 11
// 1506.787 us; speedup vs baseline: 5.4778x; 5.4778x over previous
//
#include <hip/hip_runtime.h>
#include <math.h>

#define B_ 4
#define L_ 2048
#define E_ 1024
#define H_ 16
#define D_ 64
#define FF_ 2816
#define M_ (B_*L_)     // 8192 rows
#define E4_ 4096
#define CH_ 64
#define NC_ (L_/CH_)   // 32 chunks

typedef unsigned short ushort_t;
typedef __attribute__((ext_vector_type(8))) short short8;
typedef __attribute__((ext_vector_type(4))) float f32x4;
typedef __attribute__((ext_vector_type(4))) unsigned short ushort4v;

__device__ inline ushort_t f2b(float x) {
  union { float f; unsigned u; } v; v.f = x;
  unsigned r = v.u + 0x7FFFu + ((v.u >> 16) & 1u);
  return (ushort_t)(r >> 16);
}
__device__ inline float b2f(ushort_t h) {
  union { unsigned u; float f; } v; v.u = ((unsigned)h) << 16; return v.f;
}

// ---------------------------------------------------------------------------
// reductions
// ---------------------------------------------------------------------------
__device__ inline float wave_sum(float a) {
#pragma unroll
  for (int off = 1; off < 64; off <<= 1) a += __shfl_xor(a, off);
  return a;
}
__device__ inline void wave_reduce2(float& a, float& b) {
#pragma unroll
  for (int off = 1; off < 64; off <<= 1) {
    a += __shfl_xor(a, off);
    b += __shfl_xor(b, off);
  }
}

// ---------------------------------------------------------------------------
// row LayerNorm over E_=1024 (two-pass variance), one block per row.
// ---------------------------------------------------------------------------
__global__ __launch_bounds__(256) void ln_rows(
    const float* __restrict__ in, const float* __restrict__ g,
    const float* __restrict__ bb, const float* __restrict__ res_after,
    float* __restrict__ outf, ushort_t* __restrict__ outb,
    ushort_t* __restrict__ outbl)
{
  int row = blockIdx.x;
  int t = threadIdx.x;
  float4 v = ((const float4*)(in + (size_t)row * E_))[t];
  float s = wave_sum(v.x + v.y + v.z + v.w);
  __shared__ float ra[4], rb[4];
  int w = t >> 6;
  if ((t & 63) == 0) ra[w] = s;
  __syncthreads();
  float mean = (ra[0] + ra[1] + ra[2] + ra[3]) * (1.f / E_);
  float dx = v.x - mean, dy = v.y - mean, dz = v.z - mean, dw = v.w - mean;
  float s2 = wave_sum(dx*dx + dy*dy + dz*dz + dw*dw);
  if ((t & 63) == 0) rb[w] = s2;
  __syncthreads();
  float var = (rb[0] + rb[1] + rb[2] + rb[3]) * (1.f / E_);
  float r = rsqrtf(var + 1e-5f);
  float4 gv = ((const float4*)g)[t];
  float4 bv = ((const float4*)bb)[t];
  float4 o;
  o.x = dx * r * gv.x + bv.x;
  o.y = dy * r * gv.y + bv.y;
  o.z = dz * r * gv.z + bv.z;
  o.w = dw * r * gv.w + bv.w;
  if (res_after) {
    float4 rv = ((const float4*)(res_after + (size_t)row * E_))[t];
    o.x += rv.x; o.y += rv.y; o.z += rv.z; o.w += rv.w;
  }
  if (outf) ((float4*)(outf + (size_t)row * E_))[t] = o;
  if (outb) {
    ushort4v hb; hb.x = f2b(o.x); hb.y = f2b(o.y); hb.z = f2b(o.z); hb.w = f2b(o.w);
    *(ushort4v*)(outb + (size_t)row * E_ + t * 4) = hb;
    if (outbl) {
      ushort4v lb;
      lb.x = f2b(o.x - b2f(hb.x)); lb.y = f2b(o.y - b2f(hb.y));
      lb.z = f2b(o.z - b2f(hb.z)); lb.w = f2b(o.w - b2f(hb.w));
      *(ushort4v*)(outbl + (size_t)row * E_ + t * 4) = lb;
    }
  }
}

// ---------------------------------------------------------------------------
// k <- k / max(||k||_2, 1e-5): f32 in, bf16 hi+lo out
// ---------------------------------------------------------------------------
__global__ __launch_bounds__(256) void knorm_rows(
    const float* __restrict__ kin, ushort_t* __restrict__ kh,
    ushort_t* __restrict__ kl)
{
  int row = blockIdx.x;
  int t = threadIdx.x;
  float4 v = ((const float4*)(kin + (size_t)row * E_))[t];
  float s2 = wave_sum(v.x*v.x + v.y*v.y + v.z*v.z + v.w*v.w);
  __shared__ float rb2[4];
  int w = t >> 6;
  if ((t & 63) == 0) rb2[w] = s2;
  __syncthreads();
  s2 = rb2[0] + rb2[1] + rb2[2] + rb2[3];
  float sc = 1.f / fmaxf(sqrtf(s2), 1e-5f);
  float f0 = v.x * sc, f1 = v.y * sc, f2 = v.z * sc, f3 = v.w * sc;
  ushort4v hb; hb.x = f2b(f0); hb.y = f2b(f1); hb.z = f2b(f2); hb.w = f2b(f3);
  ushort4v lb;
  lb.x = f2b(f0 - b2f(hb.x)); lb.y = f2b(f1 - b2f(hb.y));
  lb.z = f2b(f2 - b2f(hb.z)); lb.w = f2b(f3 - b2f(hb.w));
  *(ushort4v*)(kh + (size_t)row * E_ + t * 4) = hb;
  *(ushort4v*)(kl + (size_t)row * E_ + t * 4) = lb;
}

// ---------------------------------------------------------------------------
// cumsum helpers
// ---------------------------------------------------------------------------
__global__ __launch_bounds__(256) void chunk_partials(
    const float* __restrict__ x, float* __restrict__ S)
{
  int c = blockIdx.x, b = blockIdx.y, t = threadIdx.x;
  const float4* xp = (const float4*)(x + ((size_t)b * L_ + (size_t)c * CH_) * E_);
  float4 acc = make_float4(0.f, 0.f, 0.f, 0.f);
  for (int l = 0; l < CH_; ++l) {
    float4 v = xp[(size_t)l * (E_/4) + t];
    acc.x += v.x; acc.y += v.y; acc.z += v.z; acc.w += v.w;
  }
  ((float4*)(S + ((size_t)b * NC_ + c) * E_))[t] = acc;
}

__global__ __launch_bounds__(256) void scan_partials(float* __restrict__ S)
{
  int b = blockIdx.x, t = threadIdx.x;
  float4 run = make_float4(0.f, 0.f, 0.f, 0.f);
  for (int c = 0; c < NC_; ++c) {
    float4* p = (float4*)(S + ((size_t)b * NC_ + c) * E_);
    float4 v = p[t];
    p[t] = run;
    run.x += v.x; run.y += v.y; run.z += v.z; run.w += v.w;
  }
}

// ---------------------------------------------------------------------------
// align + gate (one wave per chunk,head,batch), two-pass LN
// ---------------------------------------------------------------------------
__global__ __launch_bounds__(64) void align_gate(
    const float* __restrict__ xmlp, const float* __restrict__ Sx,
    const float* __restrict__ gh, const float* __restrict__ bh,
    float* __restrict__ gated, float* __restrict__ G)
{
  int c = blockIdx.x, h = blockIdx.y, b = blockIdx.z;
  int d = threadIdx.x;
  int e = h * D_ + d;
  float xc = Sx[((size_t)b * NC_ + c) * E_ + e];
  float gsum = 0.f;
  float ghd = gh[d], bhd = bh[d];
  const float* xp = xmlp + ((size_t)b * L_ + (size_t)c * CH_) * E_ + e;
  float* gp = gated + ((size_t)b * L_ + (size_t)c * CH_) * E_ + e;
  for (int l = 0; l < CH_; ++l) {
    float xv = xp[(size_t)l * E_];
    xc += xv;
    float sx = xv, sc = xc;
    wave_reduce2(sx, sc);
    float mx = sx * (1.f/64.f), mc = sc * (1.f/64.f);
    float dx = xv - mx, dc = xc - mc;
    float vx = dx * dx, vc = dc * dc;
    wave_reduce2(vx, vc);
    vx *= (1.f/64.f); vc *= (1.f/64.f);
    float nx  = dx * rsqrtf(vx + 1e-5f) * ghd + bhd;
    float ncv = dc * rsqrtf(vc + 1e-5f) * ghd + bhd;
    float dotv = wave_sum(nx * ncv);
    float align = dotv * 0.125f;
    float sig = 1.f / (1.f + expf(-align));
    float gv = xv * sig;
    gp[(size_t)l * E_] = gv;
    gsum += gv;
  }
  G[((size_t)b * NC_ + c) * E_ + e] = gsum;
}

// ---------------------------------------------------------------------------
// t = x_mlp + cumsum(gated)
// ---------------------------------------------------------------------------
__global__ __launch_bounds__(256) void context_add(
    const float* __restrict__ gated, const float* __restrict__ Gx,
    const float* __restrict__ xmlp, float* __restrict__ t_out)
{
  int c = blockIdx.x, b = blockIdx.y, t = threadIdx.x;
  float4 run = ((const float4*)(Gx + ((size_t)b * NC_ + c) * E_))[t];
  size_t base = ((size_t)b * L_ + (size_t)c * CH_) * (E_/4);
  const float4* gp = (const float4*)gated;
  const float4* xp = (const float4*)xmlp;
  float4* op = (float4*)t_out;
  for (int l = 0; l < CH_; ++l) {
    size_t idx = base + (size_t)l * (E_/4) + t;
    float4 g = gp[idx];
    run.x += g.x; run.y += g.y; run.z += g.z; run.w += g.w;
    float4 x = xp[idx];
    float4 o;
    o.x = x.x + run.x; o.y = x.y + run.y; o.z = x.z + run.z; o.w = x.w + run.w;
    op[idx] = o;
  }
}

// ---------------------------------------------------------------------------
// transpose + convert: f32 (R x C) -> bf16 (C x R), hi + optional lo plane
// ---------------------------------------------------------------------------
__global__ __launch_bounds__(256) void wcvt_t(
    const float* __restrict__ in, ushort_t* __restrict__ outh,
    ushort_t* __restrict__ outl, int R, int C)
{
  __shared__ float t[32][33];
  int c0 = blockIdx.x * 32, r0 = blockIdx.y * 32;
  int tid = threadIdx.x;
  int r = tid >> 3, c4 = (tid & 7) * 4;
  float4 v = *(const float4*)(in + (size_t)(r0 + r) * C + c0 + c4);
  t[r][c4] = v.x; t[r][c4+1] = v.y; t[r][c4+2] = v.z; t[r][c4+3] = v.w;
  __syncthreads();
  int c = tid >> 3, r4 = (tid & 7) * 4;
  float f0 = t[r4][c], f1 = t[r4+1][c], f2 = t[r4+2][c], f3 = t[r4+3][c];
  ushort4v hb; hb.x = f2b(f0); hb.y = f2b(f1); hb.z = f2b(f2); hb.w = f2b(f3);
  *(ushort4v*)(outh + (size_t)(c0 + c) * R + r0 + r4) = hb;
  if (outl) {
    ushort4v lb;
    lb.x = f2b(f0 - b2f(hb.x)); lb.y = f2b(f1 - b2f(hb.y));
    lb.z = f2b(f2 - b2f(hb.z)); lb.w = f2b(f3 - b2f(hb.w));
    *(ushort4v*)(outl + (size_t)(c0 + c) * R + r0 + r4) = lb;
  }
}

// f32 [B][L][E] ->(scale 1/32)-> 2-plane bf16 [B][E][L]
__global__ __launch_bounds__(256) void tpose_f2p(
    const float* __restrict__ in, ushort_t* __restrict__ outh,
    ushort_t* __restrict__ outl)
{
  __shared__ float t[32][33];
  int b = blockIdx.z;
  const float* ib = in + (size_t)b * L_ * E_;
  size_t ob = (size_t)b * E_ * L_;
  int c0 = blockIdx.x * 32, r0 = blockIdx.y * 32;   // c over E, r over L
  int tid = threadIdx.x;
  int r = tid >> 3, c4 = (tid & 7) * 4;
  float4 v = *(const float4*)(ib + (size_t)(r0 + r) * E_ + c0 + c4);
  t[r][c4] = v.x; t[r][c4+1] = v.y; t[r][c4+2] = v.z; t[r][c4+3] = v.w;
  __syncthreads();
  int c = tid >> 3, r4 = (tid & 7) * 4;
  const float S = 0.03125f;   // fold /32 into v_dynT (exact: pow2 scale)
  float f0 = t[r4][c]*S, f1 = t[r4+1][c]*S, f2 = t[r4+2][c]*S, f3 = t[r4+3][c]*S;
  ushort4v hb; hb.x = f2b(f0); hb.y = f2b(f1); hb.z = f2b(f2); hb.w = f2b(f3);
  ushort4v lb;
  lb.x = f2b(f0 - b2f(hb.x)); lb.y = f2b(f1 - b2f(hb.y));
  lb.z = f2b(f2 - b2f(hb.z)); lb.w = f2b(f3 - b2f(hb.w));
  size_t oidx = ob + (size_t)(c0 + c) * L_ + r0 + r4;
  *(ushort4v*)(outh + oidx) = hb;
  *(ushort4v*)(outl + oidx) = lb;
}

// zero the strictly-above-diagonal 128x128 tiles of scores f32 output
__global__ __launch_bounds__(256) void zero_upper(float* __restrict__ sc)
{
  int bx = blockIdx.x, by = blockIdx.y, z = blockIdx.z;
  if (bx <= by) return;
  float* base = sc + (size_t)z * L_ * L_;
  int t = threadIdx.x;
  float4 zf = make_float4(0.f, 0.f, 0.f, 0.f);
#pragma unroll
  for (int i = 0; i < 16; ++i) {
    int e = t + 256 * i;
    int r = e >> 5, c4 = (e & 31) * 4;
    *(float4*)(base + (size_t)(by * 128 + r) * L_ + bx * 128 + c4) = zf;
  }
}

// ---------------------------------------------------------------------------
// MFMA GEMM, reg-staged prefetch (proven core, 128x128 only).
// MODE 0: plain bf16 (1 MFMA pass).  MODE 1: split 2-plane (3-pass).
// C(MxN) = A(MxK) @ Bt(NxK)^T ; BK=32, 4 waves, 4x4 frags.
// LDS [kw][plane][slot][8], slot = m^(kw<<1) (measured: 0 bank conflicts).
// Optional second K-segment (A2@Bt2, K2) accumulated into same acc.
// causal: 0 none, 2 kend=row0+128, 3 triangular-packed grid decode.
// ---------------------------------------------------------------------------
enum { EPI_PLAIN = 0, EPI_BIAS = 1, EPI_SILU = 2, EPI_SIG = 3,
       EPI_BIAS_RES = 4, EPI_VDYN = 5, EPI_SCL32 = 6, EPI_TRIL = 7,
       EPI_QKVG = 9 };

struct GemmP {
  const ushort_t *A, *Al, *Bt, *Btl;
  const ushort_t *A2, *A2l, *Bt2, *Bt2l;
  float *Cf, *Cf2, *Cf3;
  ushort_t *Cb, *Cbl;
  int N, K, ldA, ldB, K2, ldA2, ldB2;
  long long sA, sB, sA2, sB2, sCf, sCb, sRes;
  const float *bias, *bias1, *bias2, *bias3, *res, *aux;
  int epi, causal;
};

template <int MODE>
__global__ __launch_bounds__(256) void gemm_k(GemmP p)
{
  constexpr int NP = (MODE == 1) ? 2 : 1;
  __shared__ __align__(16) short As[4][NP][128][8];
  __shared__ __align__(16) short Bs[4][NP][128][8];

  int z = blockIdx.z;
  int bx = blockIdx.x, by = blockIdx.y;
  if (p.causal == 3) {            // triangular-packed: bx in [0, T(nry))
    int ti = bx;
    int ry = (int)((sqrtf(8.f * ti + 1.f) - 1.f) * 0.5f);
    while ((ry + 1) * (ry + 2) / 2 <= ti) ++ry;
    while (ry * (ry + 1) / 2 > ti) --ry;
    by = ry; bx = ti - ry * (ry + 1) / 2;
  }
  int row0 = by * 128, col0 = bx * 128;
  int tid = threadIdx.x;
  int lane = tid & 63, wv = tid >> 6;
  int wm = wv >> 1, wn = wv & 1;
  int lr = lane & 15, kq = lane >> 4;
  int lrx = lr ^ (kq << 1);
  int kw = tid & 3, m0 = tid >> 2, m1 = m0 + 64;
  int sl0 = m0 ^ (kw << 1), sl1 = m1 ^ (kw << 1);

  f32x4 acc[4][4] = {};

  auto kloop = [&](const ushort_t* AH, const ushort_t* ALo,
                   const ushort_t* BH, const ushort_t* BLo,
                   int ldA, int ldB, int kend) {
    size_t aoff0 = (size_t)(row0 + m0) * ldA + kw * 8;
    size_t aoff1 = (size_t)(row0 + m1) * ldA + kw * 8;
    size_t boff0 = (size_t)(col0 + m0) * ldB + kw * 8;
    size_t boff1 = (size_t)(col0 + m1) * ldB + kw * 8;
    short8 a0h, a1h, b0h, b1h, a0l, a1l, b0l, b1l;
    a0h = *(const short8*)(AH + aoff0);
    a1h = *(const short8*)(AH + aoff1);
    b0h = *(const short8*)(BH + boff0);
    b1h = *(const short8*)(BH + boff1);
    if constexpr (MODE == 1) {
      a0l = *(const short8*)(ALo + aoff0);
      a1l = *(const short8*)(ALo + aoff1);
      b0l = *(const short8*)(BLo + boff0);
      b1l = *(const short8*)(BLo + boff1);
    }
    for (int k0 = 0; k0 < kend; k0 += 32) {
      __syncthreads();                  // previous tile's reads complete
      *(short8*)&As[kw][0][sl0][0] = a0h;
      *(short8*)&As[kw][0][sl1][0] = a1h;
      *(short8*)&Bs[kw][0][sl0][0] = b0h;
      *(short8*)&Bs[kw][0][sl1][0] = b1h;
      if constexpr (MODE == 1) {
        *(short8*)&As[kw][NP-1][sl0][0] = a0l;
        *(short8*)&As[kw][NP-1][sl1][0] = a1l;
        *(short8*)&Bs[kw][NP-1][sl0][0] = b0l;
        *(short8*)&Bs[kw][NP-1][sl1][0] = b1l;
      }
      __syncthreads();
      if (k0 + 32 < kend) {             // prefetch next tile (overlaps MFMA)
        size_t kk = (size_t)k0 + 32;
        a0h = *(const short8*)(AH + aoff0 + kk);
        a1h = *(const short8*)(AH + aoff1 + kk);
        b0h = *(const short8*)(BH + boff0 + kk);
        b1h = *(const short8*)(BH + boff1 + kk);
        if constexpr (MODE == 1) {
          a0l = *(const short8*)(ALo + aoff0 + kk);
          a1l = *(const short8*)(ALo + aoff1 + kk);
          b0l = *(const short8*)(BLo + boff0 + kk);
          b1l = *(const short8*)(BLo + boff1 + kk);
        }
      }
      short8 bh[4], bl[4];
#pragma unroll
      for (int ni = 0; ni < 4; ++ni) {
        bh[ni] = *(const short8*)&Bs[kq][0][wn * 64 + ni * 16 + lrx][0];
        if constexpr (MODE == 1)
          bl[ni] = *(const short8*)&Bs[kq][NP-1][wn * 64 + ni * 16 + lrx][0];
      }
#pragma unroll
      for (int mi = 0; mi < 4; ++mi) {
        short8 ah = *(const short8*)&As[kq][0][wm * 64 + mi * 16 + lrx][0];
        short8 al;
        if constexpr (MODE == 1)
          al = *(const short8*)&As[kq][NP-1][wm * 64 + mi * 16 + lrx][0];
#pragma unroll
        for (int ni = 0; ni < 4; ++ni) {
          acc[mi][ni] = __builtin_amdgcn_mfma_f32_16x16x32_bf16(
              ah, bh[ni], acc[mi][ni], 0, 0, 0);
          if constexpr (MODE == 1) {
            acc[mi][ni] = __builtin_amdgcn_mfma_f32_16x16x32_bf16(
                al, bh[ni], acc[mi][ni], 0, 0, 0);
            acc[mi][ni] = __builtin_amdgcn_mfma_f32_16x16x32_bf16(
                ah, bl[ni], acc[mi][ni], 0, 0, 0);
          }
        }
      }
    }
  };

  int kend = p.K;
  if (p.causal == 2) { int ke = row0 + 128; kend = ke < p.K ? ke : p.K; }
  {
    const ushort_t* Ah = p.A  + (size_t)z * p.sA;
    const ushort_t* Bh = p.Bt + (size_t)z * p.sB;
    const ushort_t* Alo = (MODE == 1) ? p.Al  + (size_t)z * p.sA : nullptr;
    const ushort_t* Blo = (MODE == 1) ? p.Btl + (size_t)z * p.sB : nullptr;
    kloop(Ah, Alo, Bh, Blo, p.ldA, p.ldB, kend);
  }
  if (p.K2 > 0) {
    const ushort_t* Ah = p.A2  + (size_t)z * p.sA2;
    const ushort_t* Bh = p.Bt2 + (size_t)z * p.sB2;
    const ushort_t* Alo = (MODE == 1) ? p.A2l  + (size_t)z * p.sA2 : nullptr;
    const ushort_t* Blo = (MODE == 1) ? p.Bt2l + (size_t)z * p.sB2 : nullptr;
    kloop(Ah, Alo, Bh, Blo, p.ldA2, p.ldB2, p.K2);
  }

  int rbase = kq * 4;   // D row = (lane>>4)*4 + reg
  const float INV32 = 0.03125f;

  if (p.epi == EPI_QKVG) {              // fused q|k|v|gate, group per block
    int gi = col0 >> 10;
    int cb0 = col0 & 1023;
    const float* gb = gi == 0 ? p.bias : gi == 1 ? p.bias1
                    : gi == 2 ? p.bias2 : p.bias3;
#pragma unroll
    for (int mi = 0; mi < 4; ++mi) {
#pragma unroll
      for (int r = 0; r < 4; ++r) {
        int grow = row0 + wm * 64 + mi * 16 + rbase + r;
        size_t rowoff = (size_t)grow * 1024;
#pragma unroll
        for (int ni = 0; ni < 4; ++ni) {
          int gc = cb0 + wn * 64 + ni * 16 + lr;
          size_t idx = rowoff + gc;
          float v = acc[mi][ni][r] + gb[gc];
          if (gi == 0) {
            ushort_t hi = f2b(v);
            p.Cb[idx] = hi;
            p.Cbl[idx] = f2b(v - b2f(hi));
          } else if (gi == 1) p.Cf[idx] = v;
          else if (gi == 2) p.Cf2[idx] = v;
          else p.Cf3[idx] = 1.f / (1.f + expf(-v));
        }
      }
    }
    return;
  }

  float* Cf = p.Cf ? p.Cf + (size_t)z * p.sCf : nullptr;
  ushort_t* Cb  = p.Cb  ? p.Cb  + (size_t)z * p.sCb : nullptr;
  ushort_t* Cbl = p.Cbl ? p.Cbl + (size_t)z * p.sCb : nullptr;
  const float* res = p.res ? p.res + (size_t)z * p.sRes : nullptr;

#pragma unroll
  for (int mi = 0; mi < 4; ++mi) {
#pragma unroll
    for (int r = 0; r < 4; ++r) {
      int grow = row0 + wm * 64 + mi * 16 + rbase + r;
      size_t rowoff = (size_t)grow * p.N;
#pragma unroll
      for (int ni = 0; ni < 4; ++ni) {
        int gcol = col0 + wn * 64 + ni * 16 + lr;
        size_t idx = rowoff + gcol;
        float v = acc[mi][ni][r];
        switch (p.epi) {
          case EPI_PLAIN: break;
          case EPI_BIAS: v += p.bias[gcol]; break;
          case EPI_SILU: v += p.bias[gcol]; v = v / (1.f + expf(-v)); break;
          case EPI_SIG:  v = 1.f / (1.f + expf(-(v + p.bias[gcol]))); break;
          case EPI_BIAS_RES: v += p.bias[gcol] + res[idx]; break;
          case EPI_VDYN: v = p.aux[idx] * (res[idx] - v * INV32); break;
          case EPI_SCL32: v *= INV32; break;
          case EPI_TRIL: v = (gcol <= grow) ? v : 0.f; break;
        }
        if (Cf) Cf[idx] = v;
        if (Cb) {
          ushort_t hi = f2b(v);
          Cb[idx] = hi;
          if (Cbl) Cbl[idx] = f2b(v - b2f(hi));
        }
      }
    }
  }
}

// ---------------------------------------------------------------------------
// host orchestration
// ---------------------------------------------------------------------------
static void run_gemm(const GemmP& p, int M, int nb, int mode, hipStream_t s)
{
  dim3 grid(p.N / 128, M / 128, nb), blk(256);
  if (mode == 0) gemm_k<0><<<grid, blk, 0, s>>>(p);
  else           gemm_k<1><<<grid, blk, 0, s>>>(p);
}

extern "C" void kernel_launch(void* const* d_in, const int* in_sizes, int n_in,
                              void* d_out, int out_size, void* d_ws, size_t ws_size,
                              hipStream_t stream)
{
  const float* x      = (const float*)d_in[0];
  const float* g_norm = (const float*)d_in[1];
  const float* b_norm = (const float*)d_in[2];
  const float* W1     = (const float*)d_in[3];
  const float* b1     = (const float*)d_in[4];
  const float* W2     = (const float*)d_in[5];
  const float* b2     = (const float*)d_in[6];
  const float* g_head = (const float*)d_in[7];
  const float* b_head = (const float*)d_in[8];
  const float* memW   = (const float*)d_in[9];
  const float* g_mem  = (const float*)d_in[10];
  const float* b_mem  = (const float*)d_in[11];
  const float* W_q    = (const float*)d_in[12];
  const float* b_q    = (const float*)d_in[13];
  const float* W_k    = (const float*)d_in[14];
  const float* b_k    = (const float*)d_in[15];
  const float* W_v    = (const float*)d_in[16];
  const float* b_v    = (const float*)d_in[17];
  const float* W_g    = (const float*)d_in[18];
  const float* b_g    = (const float*)d_in[19];
  const float* W_o    = (const float*)d_in[22];
  const float* b_o    = (const float*)d_in[23];
  const float* W_op   = (const float*)d_in[24];
  const float* b_op   = (const float*)d_in[25];
  const float* g_ctx  = (const float*)d_in[26];
  const float* b_ctx  = (const float*)d_in[27];

  float* out = (float*)d_out;
  char* w = (char*)d_ws;
  auto alloc = [&](size_t bytes) { char* p = w; w += (bytes + 255) & ~(size_t)255; return p; };

  const size_t ME  = (size_t)M_ * E_;
  const size_t EE  = (size_t)E_ * E_;
  const size_t E4E = (size_t)E_ * E4_;
  const size_t BLL = (size_t)B_ * L_ * L_;

  ushort_t* W1t  = (ushort_t*)alloc((size_t)FF_ * E_ * 2);
  ushort_t* W2t  = (ushort_t*)alloc((size_t)E_ * FF_ * 2);
  ushort_t* W4   = (ushort_t*)alloc(8 * EE * 2);          // q|k|v|g hi then lo
  ushort_t* memT = (ushort_t*)alloc(2 * EE * 2);
  ushort_t* Wot  = (ushort_t*)alloc(2 * E4E * 2);
  ushort_t* Wopt = (ushort_t*)alloc(2 * E4E * 2);
  float* P0 = (float*)alloc(ME * 4);   // xmlp (live to end)
  float* P1 = (float*)alloc(ME * 4);   // gated->kraw->vdyn->out
  float* P2 = (float*)alloc(ME * 4);   // t->v->vdynT2p->outacc
  ushort_t* Q1 = (ushort_t*)alloc(2 * ME * 2);  // xnormH/ctx2p -> memout2p
  ushort_t* Q2 = (ushort_t*)alloc(2 * ME * 2);  // q2p
  ushort_t* Q3 = (ushort_t*)alloc(2 * ME * 2);  // k2p
  ushort_t* SH = (ushort_t*)alloc(2 * BLL * 2); // h1 | gateF | scores2p | outh2p
  float* Sb = (float*)alloc((size_t)B_ * NC_ * E_ * 4);
  float* Gb = (float*)alloc((size_t)B_ * NC_ * E_ * 4);
  if ((size_t)(w - (char*)d_ws) > ws_size) return;

  float* y_out  = out;
  float* sc_out = out + ME;
  ushort_t* P2u = (ushort_t*)P2;
  float* gateF  = (float*)SH;

  // weight conversion + transpose (f32 RxC -> bf16 CxR planes)
  wcvt_t<<<dim3(FF_/32, E_/32),  256, 0, stream>>>(W1,   W1t,  nullptr,        E_,  FF_);
  wcvt_t<<<dim3(E_/32,  FF_/32), 256, 0, stream>>>(W2,   W2t,  nullptr,        FF_, E_);
  wcvt_t<<<dim3(E_/32,  E_/32),  256, 0, stream>>>(W_q,  W4,        W4 + 4*EE, E_, E_);
  wcvt_t<<<dim3(E_/32,  E_/32),  256, 0, stream>>>(W_k,  W4 + EE,   W4 + 5*EE, E_, E_);
  wcvt_t<<<dim3(E_/32,  E_/32),  256, 0, stream>>>(W_v,  W4 + 2*EE, W4 + 6*EE, E_, E_);
  wcvt_t<<<dim3(E_/32,  E_/32),  256, 0, stream>>>(W_g,  W4 + 3*EE, W4 + 7*EE, E_, E_);
  wcvt_t<<<dim3(E_/32,  E_/32),  256, 0, stream>>>(memW, memT, memT + EE,      E_,  E_);
  wcvt_t<<<dim3(E4_/32, E_/32),  256, 0, stream>>>(W_o,  Wot,  Wot + E4E,      E_,  E4_);
  wcvt_t<<<dim3(E_/32,  E4_/32), 256, 0, stream>>>(W_op, Wopt, Wopt + E4E,     E4_, E_);

  GemmP p{};

  // 1. x_norm = LN(x) -> bf16 hi (Q1)
  ln_rows<<<M_, 256, 0, stream>>>(x, g_norm, b_norm, nullptr, nullptr, Q1, nullptr);
  // 2. h1 = silu(x_norm @ W1 + b1) -> SH plain bf16
  p = GemmP{}; p.A = Q1; p.Bt = W1t; p.Cb = SH;
  p.N = FF_; p.K = E_; p.ldA = E_; p.ldB = E_;
  p.bias = b1; p.epi = EPI_SILU;
  run_gemm(p, M_, 1, 0, stream);
  // 3. x_mlp = x + h1 @ W2 + b2 -> P0
  p = GemmP{}; p.A = SH; p.Bt = W2t; p.Cf = P0;
  p.N = E_; p.K = FF_; p.ldA = FF_; p.ldB = FF_;
  p.bias = b2; p.res = x; p.epi = EPI_BIAS_RES;
  run_gemm(p, M_, 1, 0, stream);
  // 4-8. cumsum gating chain
  chunk_partials<<<dim3(NC_, B_), 256, 0, stream>>>(P0, Sb);
  scan_partials<<<B_, 256, 0, stream>>>(Sb);
  align_gate<<<dim3(NC_, H_, B_), 64, 0, stream>>>(P0, Sb, g_head, b_head, P1, Gb);
  scan_partials<<<B_, 256, 0, stream>>>(Gb);
  context_add<<<dim3(NC_, B_), 256, 0, stream>>>(P1, Gb, P0, P2);
  // 9. ctx = LN(t) -> Q1 2p
  ln_rows<<<M_, 256, 0, stream>>>(P2, g_mem, b_mem, nullptr, nullptr, Q1, Q1 + ME);
  // 10. fused QKVG (N=4096): q->Q2 2p, kraw->P1, v->P2, gate->gateF
  p = GemmP{}; p.A = Q1; p.Al = Q1 + ME; p.Bt = W4; p.Btl = W4 + 4*EE;
  p.N = E4_; p.K = E_; p.ldA = E_; p.ldB = E_;
  p.Cb = Q2; p.Cbl = Q2 + ME; p.Cf = P1; p.Cf2 = P2; p.Cf3 = gateF;
  p.bias = b_q; p.bias1 = b_k; p.bias2 = b_v; p.bias3 = b_g;
  p.epi = EPI_QKVG;
  run_gemm(p, M_, 1, 1, stream);
  // 11. knorm: P1(kraw) -> Q3 2p
  knorm_rows<<<M_, 256, 0, stream>>>(P1, Q3, Q3 + ME);
  // 12. v_dyn = gate * (v - (k @ mem)/32) -> P1 f32
  p = GemmP{}; p.A = Q3; p.Al = Q3 + ME; p.Bt = memT; p.Btl = memT + EE;
  p.N = E_; p.K = E_; p.ldA = E_; p.ldB = E_;
  p.Cf = P1; p.res = P2; p.aux = gateF; p.epi = EPI_VDYN;
  run_gemm(p, M_, 1, 1, stream);
  // 13. vdynT/32 2p [B][E][L] -> P2u planes
  tpose_f2p<<<dim3(E_/32, L_/32, B_), 256, 0, stream>>>(P1, P2u, P2u + ME);
  // 14a. zero upper triangle of f32 scores output
  zero_upper<<<dim3(16, 16, B_), 256, 0, stream>>>(sc_out);
  // 14b. scores = tril(q @ k^T) -> f32 d_out + 2p SH  [triangular grid]
  p = GemmP{}; p.A = Q2; p.Al = Q2 + ME; p.Bt = Q3; p.Btl = Q3 + ME;
  p.N = L_; p.K = E_; p.ldA = E_; p.ldB = E_;
  p.sA = (long long)L_ * E_; p.sB = (long long)L_ * E_;
  p.Cf = sc_out; p.sCf = (long long)L_ * L_;
  p.Cb = SH; p.Cbl = SH + BLL; p.sCb = (long long)L_ * L_;
  p.epi = EPI_TRIL; p.causal = 3;
  gemm_k<1><<<dim3(136, 1, B_), 256, 0, stream>>>(p);
  // 15. mem_out = (q@mem + scores@(v_dyn/32))/32 -> Q1 2p  [fused 2-segment]
  p = GemmP{}; p.A = SH; p.Al = SH + BLL; p.Bt = P2u; p.Btl = P2u + ME;
  p.N = E_; p.K = L_; p.ldA = L_; p.ldB = L_;
  p.sA = (long long)L_ * L_; p.sB = (long long)E_ * L_;
  p.A2 = Q2; p.A2l = Q2 + ME; p.Bt2 = memT; p.Bt2l = memT + EE;
  p.K2 = E_; p.ldA2 = E_; p.ldB2 = E_;
  p.sA2 = (long long)L_ * E_; p.sB2 = 0;
  p.Cb = Q1; p.Cbl = Q1 + ME; p.sCb = (long long)L_ * E_;
  p.epi = EPI_SCL32; p.causal = 2;
  run_gemm(p, L_, B_, 1, stream);
  // 16-17. output MLP, E4 chunked by 2048
  const size_t SHLO = (size_t)M_ * 2048;
  for (int c = 0; c < 2; ++c) {
    p = GemmP{}; p.A = Q1; p.Al = Q1 + ME;
    p.Bt = Wot + (size_t)c * 2048 * E_; p.Btl = Wot + E4E + (size_t)c * 2048 * E_;
    p.N = 2048; p.K = E_; p.ldA = E_; p.ldB = E_;
    p.Cb = SH; p.Cbl = SH + SHLO;
    p.bias = b_o + c * 2048; p.epi = EPI_SILU;
    run_gemm(p, M_, 1, 1, stream);
    p = GemmP{}; p.A = SH; p.Al = SH + SHLO;
    p.Bt = Wopt + (size_t)c * 2048; p.Btl = Wopt + E4E + (size_t)c * 2048;
    p.N = E_; p.K = 2048; p.ldA = 2048; p.ldB = E4_;
    if (c == 0) { p.Cf = P2; p.epi = EPI_PLAIN; }
    else { p.Cf = P1; p.res = P2; p.bias = b_op; p.epi = EPI_BIAS_RES; }
    run_gemm(p, M_, 1, 1, stream);
  }
  // 18. y = x_mlp + LN(out)
  ln_rows<<<M_, 256, 0, stream>>>(P1, g_ctx, b_ctx, P0, y_out, nullptr, nullptr);
}